// Round 1
// baseline (5406.169 us; speedup 1.0000x reference)
//
#include <hip/hip_runtime.h>
#include <math.h>

// Problem constants
static constexpr int cB = 32;
static constexpr int cT = 1024;
static constexpr int cH = 128;
static constexpr int cD = 256;   // 2H
static constexpr int cN = 2048;  // H*POOL
static constexpr int cM = cB * cT; // 32768

// ---------------------------------------------------------------------------
// GEMM with optional 16-wide maxpool epilogue and optional accumulator init
// C = maybe_pool( A[M x K] @ W[K x N] + init[b(n-row) x N] )
// BM=128 BN=128 BK=32, 256 threads, thread tile 4 rows x 16 consecutive cols
// ---------------------------------------------------------------------------
__global__ __launch_bounds__(256, 3)
void gemm_pool_kernel(const float* __restrict__ A, int K,
                      const float* __restrict__ W, int N,
                      const float* __restrict__ initv, int init_bstride,
                      float* __restrict__ out, int do_pool)
{
    constexpr int BM = 128, BN = 128, BK = 32;
    __shared__ float As[BK][BM + 4];  // A transposed: As[k][m]
    __shared__ float Bs[BK][BN + 4];

    const int tid = threadIdx.x;
    const int tx = tid & 7;    // column group: c0 = tx*16
    const int ty = tid >> 3;   // row group:    r0 = ty*4
    const int m0 = blockIdx.y * BM;
    const int n0 = blockIdx.x * BN;

    float acc[4][16];
    if (initv) {
        const int brow = m0 / cT;  // BM=128 divides T=1024 -> whole block same b
        const float* ip = initv + (size_t)brow * init_bstride + n0 + tx * 16;
        #pragma unroll
        for (int j = 0; j < 16; ++j) {
            float v = ip[j];
            #pragma unroll
            for (int i = 0; i < 4; ++i) acc[i][j] = v;
        }
    } else {
        #pragma unroll
        for (int i = 0; i < 4; ++i)
            #pragma unroll
            for (int j = 0; j < 16; ++j) acc[i][j] = 0.f;
    }

    for (int k0 = 0; k0 < K; k0 += BK) {
        // stage A tile (BM x BK), transposed into LDS
        #pragma unroll
        for (int q = 0; q < 4; ++q) {
            int f = tid + q * 256;          // quad id, 1024 quads
            int row = f >> 3;               // 8 quads per row (32 floats)
            int kq = (f & 7) << 2;
            float4 v = *(const float4*)(A + (size_t)(m0 + row) * K + (k0 + kq));
            As[kq + 0][row] = v.x;
            As[kq + 1][row] = v.y;
            As[kq + 2][row] = v.z;
            As[kq + 3][row] = v.w;
        }
        // stage B tile (BK x BN)
        #pragma unroll
        for (int q = 0; q < 4; ++q) {
            int f = tid + q * 256;
            int kr = f >> 5;                // 32 quads per row (128 floats)
            int nq = (f & 31) << 2;
            *(float4*)(&Bs[kr][nq]) = *(const float4*)(W + (size_t)(k0 + kr) * N + n0 + nq);
        }
        __syncthreads();

        #pragma unroll 4
        for (int k = 0; k < BK; ++k) {
            float4 a4 = *(const float4*)(&As[k][ty * 4]);
            float bv[16];
            *(float4*)(&bv[0])  = *(const float4*)(&Bs[k][tx * 16 + 0]);
            *(float4*)(&bv[4])  = *(const float4*)(&Bs[k][tx * 16 + 4]);
            *(float4*)(&bv[8])  = *(const float4*)(&Bs[k][tx * 16 + 8]);
            *(float4*)(&bv[12]) = *(const float4*)(&Bs[k][tx * 16 + 12]);
            float av[4] = {a4.x, a4.y, a4.z, a4.w};
            #pragma unroll
            for (int i = 0; i < 4; ++i)
                #pragma unroll
                for (int j = 0; j < 16; ++j)
                    acc[i][j] = fmaf(av[i], bv[j], acc[i][j]);
        }
        __syncthreads();
    }

    if (do_pool) {
        const int NP = N / 16;
        #pragma unroll
        for (int i = 0; i < 4; ++i) {
            float mx = acc[i][0];
            #pragma unroll
            for (int j = 1; j < 16; ++j) mx = fmaxf(mx, acc[i][j]);
            out[(size_t)(m0 + ty * 4 + i) * NP + (n0 / 16) + tx] = mx;
        }
    } else {
        #pragma unroll
        for (int i = 0; i < 4; ++i) {
            float* op = out + (size_t)(m0 + ty * 4 + i) * N + n0 + tx * 16;
            *(float4*)(op + 0)  = make_float4(acc[i][0], acc[i][1], acc[i][2], acc[i][3]);
            *(float4*)(op + 4)  = make_float4(acc[i][4], acc[i][5], acc[i][6], acc[i][7]);
            *(float4*)(op + 8)  = make_float4(acc[i][8], acc[i][9], acc[i][10], acc[i][11]);
            *(float4*)(op + 12) = make_float4(acc[i][12], acc[i][13], acc[i][14], acc[i][15]);
        }
    }
}

// ---------------------------------------------------------------------------
// m1[m][o] = max_p( A1[m][o*16+p] + rterm[b][o*16+p] )   (precompute path)
// ---------------------------------------------------------------------------
__global__ void m1_from_a1_kernel(const float* __restrict__ A1,
                                  const float* __restrict__ rterm,
                                  float* __restrict__ m1)
{
    int idx = blockIdx.x * 256 + threadIdx.x;   // [0, 32768*128)
    int m = idx >> 7;
    int o = idx & 127;
    int b = m >> 10;
    const float4* a  = (const float4*)(A1 + (size_t)m * cN + o * 16);
    const float4* rt = (const float4*)(rterm + (size_t)b * cN + o * 16);
    float mx = -3.4e38f;
    #pragma unroll
    for (int q = 0; q < 4; ++q) {
        float4 av = a[q];
        float4 rv = rt[q];
        mx = fmaxf(mx, fmaxf(fmaxf(av.x + rv.x, av.y + rv.y),
                             fmaxf(av.z + rv.z, av.w + rv.w)));
    }
    m1[idx] = mx;
}

// ---------------------------------------------------------------------------
// r[b][j] = tanh( concat([h,us,ue])[b] . WDw[:,j] + WDb[j] )
// ---------------------------------------------------------------------------
__global__ void r_kernel(const float* __restrict__ h, const float* __restrict__ us,
                         const float* __restrict__ ue,
                         const float* __restrict__ WDw, const float* __restrict__ WDb,
                         float* __restrict__ r)
{
    int b = blockIdx.x;
    int j = threadIdx.x;  // 128 threads
    __shared__ float x[640];
    x[j]       = h[b * cH + j];
    x[128 + j] = us[b * cD + j];
    x[256 + j] = us[b * cD + 128 + j];
    x[384 + j] = ue[b * cD + j];
    x[512 + j] = ue[b * cD + 128 + j];
    __syncthreads();
    float s = WDb[j];
    for (int k = 0; k < 640; ++k) s = fmaf(x[k], WDw[(size_t)k * cH + j], s);
    r[b * cH + j] = tanhf(s);
}

// ---------------------------------------------------------------------------
// rterm[b][n] = r[b] . W1r[:,n] + W1b[n]    (W1r = rows 256..383 of W1w)
// ---------------------------------------------------------------------------
__global__ void rterm_kernel(const float* __restrict__ r, const float* __restrict__ W1r,
                             const float* __restrict__ W1b, float* __restrict__ rterm)
{
    int b = blockIdx.y;
    int n = blockIdx.x * 256 + threadIdx.x;  // grid (8,32)
    __shared__ float rs[128];
    if (threadIdx.x < 128) rs[threadIdx.x] = r[b * cH + threadIdx.x];
    __syncthreads();
    float s = W1b[n];
    for (int k = 0; k < 128; ++k) s = fmaf(rs[k], W1r[(size_t)k * cN + n], s);
    rterm[(size_t)b * cN + n] = s;
}

// ---------------------------------------------------------------------------
// score[m] = max_p( concat([m1,m2])[m] . W3w[:,p] + W3b[p] ) -> ent region
// block: 16 rows x 16 pool lanes
// ---------------------------------------------------------------------------
__global__ __launch_bounds__(256)
void score_kernel(const float* __restrict__ m1, const float* __restrict__ m2,
                  const float* __restrict__ W3w, const float* __restrict__ W3b,
                  float* __restrict__ ent)
{
    __shared__ float xs[16][257];
    __shared__ float wsh[256 * 16];
    int tid = threadIdx.x;
    int m0 = blockIdx.x * 16;
    #pragma unroll
    for (int q = 0; q < 16; ++q) wsh[tid + q * 256] = W3w[tid + q * 256];
    #pragma unroll
    for (int q = 0; q < 8; ++q) {
        int f = tid + q * 256;
        int rl = f >> 7, col = f & 127;
        xs[rl][col]       = m1[(size_t)(m0 + rl) * cH + col];
        xs[rl][128 + col] = m2[(size_t)(m0 + rl) * cH + col];
    }
    __syncthreads();
    int rl = tid >> 4, p = tid & 15;
    float s = W3b[p];
    for (int k = 0; k < 256; ++k) s = fmaf(xs[rl][k], wsh[k * 16 + p], s);
    #pragma unroll
    for (int off = 8; off; off >>= 1) s = fmaxf(s, __shfl_xor(s, off));
    if (p == 0) ent[m0 + rl] = s;
}

// ---------------------------------------------------------------------------
// argmax over T per batch (first-occurrence ties, numpy semantics),
// write float index into d_out slot, gather U row into us/ue
// ---------------------------------------------------------------------------
__global__ void argmax_kernel(const float* __restrict__ sc, const float* __restrict__ U,
                              float* __restrict__ uvec, float* __restrict__ outidx)
{
    int b = blockIdx.x;
    int tid = threadIdx.x;  // 256
    float bv = -3.4e38f;
    int bi = 0x7fffffff;
    for (int t = tid; t < cT; t += 256) {
        float v = sc[b * cT + t];
        if (v > bv || (v == bv && t < bi)) { bv = v; bi = t; }
    }
    __shared__ float vs[256];
    __shared__ int   is[256];
    vs[tid] = bv; is[tid] = bi;
    __syncthreads();
    for (int s = 128; s > 0; s >>= 1) {
        if (tid < s) {
            if (vs[tid + s] > vs[tid] ||
                (vs[tid + s] == vs[tid] && is[tid + s] < is[tid])) {
                vs[tid] = vs[tid + s];
                is[tid] = is[tid + s];
            }
        }
        __syncthreads();
    }
    int best = is[0];
    if (tid == 0) outidx[b] = (float)best;
    uvec[b * cD + tid % cD] = U[((size_t)b * cT + best) * cD + (tid % cD)];
}

// ---------------------------------------------------------------------------
// LSTM cell: x = concat([us,ue]) (512), gates = x@wih^T + bih + h@whh^T + bhh
// ---------------------------------------------------------------------------
__global__ void lstm_kernel(const float* __restrict__ us, const float* __restrict__ ue,
                            float* __restrict__ h, float* __restrict__ c,
                            const float* __restrict__ wih, const float* __restrict__ whh,
                            const float* __restrict__ bih, const float* __restrict__ bhh)
{
    int b = blockIdx.x;
    int j = threadIdx.x;  // 128
    __shared__ float x[512];
    __shared__ float hh[128];
    x[j]       = us[b * cD + j];
    x[128 + j] = us[b * cD + 128 + j];
    x[256 + j] = ue[b * cD + j];
    x[384 + j] = ue[b * cD + 128 + j];
    hh[j] = h[b * cH + j];
    __syncthreads();
    float g4[4];
    #pragma unroll
    for (int gi = 0; gi < 4; ++gi) {
        int row = gi * 128 + j;
        float s = bih[row] + bhh[row];
        const float* wr = wih + (size_t)row * 512;
        for (int k = 0; k < 512; ++k) s = fmaf(x[k], wr[k], s);
        const float* wr2 = whh + (size_t)row * 128;
        for (int k = 0; k < 128; ++k) s = fmaf(hh[k], wr2[k], s);
        g4[gi] = s;
    }
    float i_ = 1.f / (1.f + expf(-g4[0]));
    float f_ = 1.f / (1.f + expf(-g4[1]));
    float g_ = tanhf(g4[2]);
    float o_ = 1.f / (1.f + expf(-g4[3]));
    float c2 = f_ * c[b * cH + j] + i_ * g_;
    float h2 = o_ * tanhf(c2);
    c[b * cH + j] = c2;
    h[b * cH + j] = h2;
}

__global__ void init_kernel(const float* __restrict__ U, float* __restrict__ us,
                            float* __restrict__ ue, float* __restrict__ h,
                            float* __restrict__ c)
{
    int i = blockIdx.x * 256 + threadIdx.x;  // 8192 threads
    if (i < cB * cD) {
        int b = i >> 8, d = i & 255;
        us[i] = U[((size_t)b * cT + 0) * cD + d];
        ue[i] = U[((size_t)b * cT + 1) * cD + d];
    }
    if (i < cB * cH) { h[i] = 0.f; c[i] = 0.f; }
}

// ---------------------------------------------------------------------------
extern "C" void kernel_launch(void* const* d_in, const int* in_sizes, int n_in,
                              void* d_out, int out_size, void* d_ws, size_t ws_size,
                              hipStream_t stream)
{
    const float* U = (const float*)d_in[0];
    const float* WD_w[2] = {(const float*)d_in[1], (const float*)d_in[9]};
    const float* WD_b[2] = {(const float*)d_in[2], (const float*)d_in[10]};
    const float* W1_w[2] = {(const float*)d_in[3], (const float*)d_in[11]};
    const float* W1_b[2] = {(const float*)d_in[4], (const float*)d_in[12]};
    const float* W2_w[2] = {(const float*)d_in[5], (const float*)d_in[13]};
    const float* W2_b[2] = {(const float*)d_in[6], (const float*)d_in[14]};
    const float* W3_w[2] = {(const float*)d_in[7], (const float*)d_in[15]};
    const float* W3_b[2] = {(const float*)d_in[8], (const float*)d_in[16]};
    const float* wih = (const float*)d_in[17];
    const float* whh = (const float*)d_in[18];
    const float* bih = (const float*)d_in[19];
    const float* bhh = (const float*)d_in[20];

    float* ws = (float*)d_ws;
    float* m1 = ws;                               // 32768*128
    float* m2 = m1 + (size_t)cM * cH;             // 32768*128
    float* us = m2 + (size_t)cM * cH;             // 32*256
    float* ue = us + cB * cD;
    float* h  = ue + cB * cD;                     // 32*128
    float* c  = h + cB * cH;
    float* r  = c + cB * cH;
    float* rterm = r + cB * cH;                   // 32*2048
    float* A1[2];
    A1[0] = rterm + (size_t)cB * cN;
    A1[1] = A1[0] + (size_t)cM * cN;              // 32768*2048 each
    size_t pre_floats = (size_t)(A1[1] - ws) + (size_t)cM * cN;
    bool pre = ws_size >= pre_floats * sizeof(float);

    float* outf = (float*)d_out;

    init_kernel<<<32, 256, 0, stream>>>(U, us, ue, h, c);

    if (pre) {
        // A1 = U @ W1w[0:256,:]  once per weight set (constant across iterations)
        for (int sd = 0; sd < 2; ++sd)
            gemm_pool_kernel<<<dim3(16, 256), 256, 0, stream>>>(
                U, cD, W1_w[sd], cN, nullptr, 0, A1[sd], 0);
    }

    for (int it = 0; it < 4; ++it) {
        for (int sd = 0; sd < 2; ++sd) {
            r_kernel<<<32, 128, 0, stream>>>(h, us, ue, WD_w[sd], WD_b[sd], r);
            rterm_kernel<<<dim3(8, 32), 256, 0, stream>>>(
                r, W1_w[sd] + (size_t)256 * cN, W1_b[sd], rterm);
            if (pre) {
                m1_from_a1_kernel<<<16384, 256, 0, stream>>>(A1[sd], rterm, m1);
            } else {
                gemm_pool_kernel<<<dim3(16, 256), 256, 0, stream>>>(
                    U, cD, W1_w[sd], cN, rterm, cN, m1, 1);
            }
            gemm_pool_kernel<<<dim3(16, 256), 256, 0, stream>>>(
                m1, cH, W2_w[sd], cN, W2_b[sd], 0, m2, 1);
            float* ent = outf + 64 + (size_t)(it * 2 + sd) * cB * cT;
            score_kernel<<<2048, 256, 0, stream>>>(m1, m2, W3_w[sd], W3_b[sd], ent);
            argmax_kernel<<<32, 256, 0, stream>>>(ent, U, sd ? ue : us,
                                                  outf + (sd ? 32 : 0));
        }
        lstm_kernel<<<32, 128, 0, stream>>>(us, ue, h, c, wih, whh, bih, bhh);
    }
}